// Round 6
// baseline (3808.002 us; speedup 1.0000x reference)
//
#include <hip/hip_runtime.h>
#include <math.h>

#define B_SZ 1024
#define N_SZ 100000
#define D_SZ 512
#define NBLK 3125   // N/32 row-tiles (exact: 100000 = 3125*32)

typedef __attribute__((ext_vector_type(8))) short short8;
typedef __attribute__((ext_vector_type(16))) float float16;

__device__ __forceinline__ unsigned f2bf(float x) {
    unsigned u = __float_as_uint(x);
    u += 0x7FFFu + ((u >> 16) & 1u);
    return u >> 16;                       // RNE bf16 bits in low 16
}
__device__ __forceinline__ float bf2f(unsigned h) {
    return __uint_as_float(h << 16);
}

// ---------------- PRE: split dataset to Yh/Yl, transposed Yt, norms; split X ----
__global__ __launch_bounds__(256) void pre_kernel(
    const float* __restrict__ ds, const float* __restrict__ x_t,
    short* __restrict__ Yh, short* __restrict__ Yl, short* __restrict__ Yt,
    short* __restrict__ Xh, short* __restrict__ Xl, float* __restrict__ norms)
{
    __shared__ unsigned short YS[32 * 512];   // hi tile, [n][d]
    const int bx = blockIdx.x, tid = threadIdx.x;
    if (bx < NBLK) {
        const int row = tid >> 3, seg = tid & 7;
        const size_t g = (size_t)(bx * 32 + row) * 512 + seg * 64;
        const int ls = row * 512 + seg * 64;
        float nrm = 0.f;
        #pragma unroll
        for (int i = 0; i < 16; i++) {
            float4 v = *(const float4*)(ds + g + i * 4);
            nrm += v.x*v.x + v.y*v.y + v.z*v.z + v.w*v.w;
            unsigned h0 = f2bf(v.x), h1 = f2bf(v.y), h2 = f2bf(v.z), h3 = f2bf(v.w);
            unsigned l0 = f2bf(v.x - bf2f(h0)), l1 = f2bf(v.y - bf2f(h1));
            unsigned l2 = f2bf(v.z - bf2f(h2)), l3 = f2bf(v.w - bf2f(h3));
            uint2 hw = make_uint2(h0 | (h1 << 16), h2 | (h3 << 16));
            uint2 lw = make_uint2(l0 | (l1 << 16), l2 | (l3 << 16));
            *(uint2*)(Yh + g + i * 4) = hw;
            *(uint2*)(Yl + g + i * 4) = lw;
            *(uint2*)(YS + ls + i * 4) = hw;
        }
        nrm += __shfl_xor(nrm, 1, 64);
        nrm += __shfl_xor(nrm, 2, 64);
        nrm += __shfl_xor(nrm, 4, 64);
        if ((tid & 7) == 0) norms[bx * 32 + row] = nrm;
        __syncthreads();
        // transposed block Yt[bx][d][n']  (rows of 32 bf16 = 64 B)
        #pragma unroll
        for (int r = 0; r < 2; r++) {
            const int d = tid + r * 256;
            unsigned w[16];
            #pragma unroll
            for (int j = 0; j < 16; j++) {
                unsigned lo = YS[(2 * j) * 512 + d];
                unsigned hi = YS[(2 * j + 1) * 512 + d];
                w[j] = lo | (hi << 16);
            }
            uint4* dst = (uint4*)(Yt + (size_t)bx * 16384 + d * 32);
            dst[0] = make_uint4(w[0], w[1], w[2], w[3]);
            dst[1] = make_uint4(w[4], w[5], w[6], w[7]);
            dst[2] = make_uint4(w[8], w[9], w[10], w[11]);
            dst[3] = make_uint4(w[12], w[13], w[14], w[15]);
        }
    } else {
        const int xb = bx - NBLK;   // 0..31, X split: 1024x512 f32
        #pragma unroll
        for (int k = 0; k < 16; k++) {
            const size_t i4 = (size_t)xb * 4096 + k * 256 + tid;
            float4 v = *(const float4*)(x_t + i4 * 4);
            unsigned h0 = f2bf(v.x), h1 = f2bf(v.y), h2 = f2bf(v.z), h3 = f2bf(v.w);
            unsigned l0 = f2bf(v.x - bf2f(h0)), l1 = f2bf(v.y - bf2f(h1));
            unsigned l2 = f2bf(v.z - bf2f(h2)), l3 = f2bf(v.w - bf2f(h3));
            *(uint2*)(Xh + i4 * 4) = make_uint2(h0 | (h1 << 16), h2 | (h3 << 16));
            *(uint2*)(Xl + i4 * 4) = make_uint2(l0 | (l1 << 16), l2 | (l3 << 16));
        }
    }
}

// ---------------- MAIN: producer/consumer MFMA flash, Q-tile 32 ----------------
// 512 thr = 8 waves, 2 blocks/CU. Waves 0-3: S = Y.X^T (4-way k-split, 3 bf16
// passes) atomically reduced into `slots`; softmax -> bf16 Pb (k-major).
// Waves 4-7: O += Yt^T.P^T for a 128-dim slice, one tile behind.
// Y staged k-major: LDS granule (g*32+n) so A-frag b128 reads are
// lane-contiguous (conflict-free); global side uses per-lane scatter.
__global__ __launch_bounds__(512, 4) void attn_kernel(
    const float* __restrict__ t,
    const short* __restrict__ Xh, const short* __restrict__ Xl,
    const short* __restrict__ Yh, const short* __restrict__ Yl,
    const short* __restrict__ Yt, const float* __restrict__ norms,
    float* __restrict__ m_part, float* __restrict__ l_part,
    float* __restrict__ acc_part, int chunk)
{
    __shared__ short Ykm[32768];     // 64 KB: [hl][g 0..63][n 0..31][8]
    __shared__ float slots[32 * 33]; // 4.2 KB, atomic k-reduce, pitch 33
    __shared__ short Pb[4 * 32 * 8]; // 2 KB: [gk][q][8] bf16
    __shared__ float c1A[32], c2A[32], mAs[32], lAs[32], alA[32], nrmL[32];

    const int tid = threadIdx.x;
    const int wave = tid >> 6, lane = tid & 63;
    const int half = lane >> 5, l31 = lane & 31;
    const int qb = blockIdx.x * 32;
    const int s = blockIdx.y;
    const int n0s = s * chunk;
    const int n1 = min(N_SZ, n0s + chunk);
    const int numTiles = (n1 - n0s) >> 5;   // chunk%32==0, N%32==0: all full

    if (tid < 32) {
        float tv = t[qb + tid];
        float bt = 1.0f - tv;
        float i2 = 1.0f / (2.0f * bt * bt);
        c1A[tid] = 2.0f * tv * i2;
        c2A[tid] = tv * tv * i2;
        mAs[tid] = -1e30f;
        lAs[tid] = 0.0f;
        alA[tid] = 0.0f;
    }
    for (int i = tid; i < 32 * 33; i += 512) slots[i] = 0.0f;
    __syncthreads();

    if (wave < 4) {
        // ================= PRODUCER =================
        const int w = wave;
        short8 XF[8][2];   // B-frags (q=l31), 64 VGPR, persistent
        #pragma unroll
        for (int kc = 0; kc < 8; kc++) {
            size_t off = (size_t)(qb + l31) * 512 + w * 128 + kc * 16 + half * 8;
            XF[kc][0] = *(const short8*)(Xh + off);
            XF[kc][1] = *(const short8*)(Xl + off);
        }

        for (int it = 0; it <= numTiles; ++it) {
            if (it < numTiles) {   // stage tile it, k-major
                int n0 = n0s + it * 32;
                #pragma unroll
                for (int j = 0; j < 16; j++) {
                    int i = w * 16 + j;             // 0..63 instruction id
                    int g = (2 * i + half) & 63;    // k-granule (8 dims)
                    const short* src = ((i >> 5) ? Yl : Yh)
                                     + (size_t)(n0 + l31) * 512 + g * 8;
                    __builtin_amdgcn_global_load_lds(
                        (const __attribute__((address_space(1))) unsigned int*)src,
                        (__attribute__((address_space(3))) unsigned int*)&Ykm[i * 512],
                        16, 0, 0);
                }
                if (w == 0 && lane < 32) nrmL[lane] = norms[n0 + lane];
            }
            __syncthreads();   // (a) tile staged

            if (it < numTiles) {
                float16 S;
                #pragma unroll
                for (int e = 0; e < 16; e++) S[e] = 0.f;
                #pragma unroll
                for (int kc = 0; kc < 8; kc++) {
                    int g = w * 16 + kc * 2 + half;
                    short8 Ah = *(const short8*)(Ykm + (g * 32 + l31) * 8);
                    short8 Al = *(const short8*)(Ykm + 16384 + (g * 32 + l31) * 8);
                    S = __builtin_amdgcn_mfma_f32_32x32x16_bf16(Ah, XF[kc][0], S, 0, 0, 0);
                    S = __builtin_amdgcn_mfma_f32_32x32x16_bf16(Ah, XF[kc][1], S, 0, 0, 0);
                    S = __builtin_amdgcn_mfma_f32_32x32x16_bf16(Al, XF[kc][0], S, 0, 0, 0);
                }
                float* rowp = slots + l31 * 33;   // row = q, conflict-free stride
                #pragma unroll
                for (int r = 0; r < 16; r++) {
                    int n = (r & 3) + 8 * (r >> 2) + 4 * half;
                    atomicAdd(rowp + n, S[r]);
                }
            }
            __syncthreads();   // (b) S reduced

            if (it < numTiles) {   // softmax -> Pb (bf16, k-major), re-zero slots
                int ql = lane >> 3, nq = lane & 7;
                int q = w * 8 + ql;
                float c1q = c1A[q], c2q = c2A[q];
                float lg[4];
                float mt = -1e30f;
                #pragma unroll
                for (int j = 0; j < 4; j++) {
                    int n = nq * 4 + j;
                    float dd = slots[q * 33 + n];
                    slots[q * 33 + n] = 0.0f;
                    lg[j] = c1q * dd - c2q * nrmL[n];
                    mt = fmaxf(mt, lg[j]);
                }
                mt = fmaxf(mt, __shfl_xor(mt, 1, 64));
                mt = fmaxf(mt, __shfl_xor(mt, 2, 64));
                mt = fmaxf(mt, __shfl_xor(mt, 4, 64));
                float mo = mAs[q];
                float mn = fmaxf(mo, mt);
                float al = __expf(mo - mn);
                float ls = 0.f;
                unsigned pk[4];
                #pragma unroll
                for (int j = 0; j < 4; j++) {
                    float p = __expf(lg[j] - mn);
                    ls += p;
                    pk[j] = f2bf(p);
                }
                ls += __shfl_xor(ls, 1, 64);
                ls += __shfl_xor(ls, 2, 64);
                ls += __shfl_xor(ls, 4, 64);
                uint2 wv = make_uint2(pk[0] | (pk[1] << 16), pk[2] | (pk[3] << 16));
                *(uint2*)(Pb + ((nq >> 1) * 32 + q) * 8 + (nq & 1) * 4) = wv;
                if (nq == 0) {
                    mAs[q] = mn;
                    lAs[q] = lAs[q] * al + ls;
                    alA[q] = al;
                }
            }
            __syncthreads();   // (c) Pb/alpha ready
        }
        if (tid < 32) {
            m_part[(size_t)s * B_SZ + qb + tid] = mAs[tid];
            l_part[(size_t)s * B_SZ + qb + tid] = lAs[tid];
        }
    } else {
        // ================= CONSUMER =================
        const int dbase = (wave - 4) * 128;
        float16 O[4];
        #pragma unroll
        for (int dt = 0; dt < 4; dt++)
            #pragma unroll
            for (int e = 0; e < 16; e++) O[dt][e] = 0.f;

        for (int it = 0; it <= numTiles; ++it) {
            __syncthreads();   // (a)
            if (it > 0) {      // PV(it-1)
                int blk = (n0s + (it - 1) * 32) >> 5;
                const short* yb = Yt + (size_t)blk * 16384;
                float al = alA[l31];
                short8 BF[2];
                #pragma unroll
                for (int kc = 0; kc < 2; kc++)
                    BF[kc] = *(const short8*)(Pb + ((kc * 2 + half) * 32 + l31) * 8);
                #pragma unroll
                for (int dt = 0; dt < 4; dt++) O[dt] *= al;
                #pragma unroll
                for (int dt = 0; dt < 4; dt++) {
                    #pragma unroll
                    for (int kc = 0; kc < 2; kc++) {
                        short8 AF = *(const short8*)(
                            yb + (dbase + dt * 32 + l31) * 32 + kc * 16 + half * 8);
                        O[dt] = __builtin_amdgcn_mfma_f32_32x32x16_bf16(
                            AF, BF[kc], O[dt], 0, 0, 0);
                    }
                }
            }
            __syncthreads();   // (b)
            __syncthreads();   // (c)
        }
        // write O partials -> acc_part[s][q][d]
        #pragma unroll
        for (int dt = 0; dt < 4; dt++) {
            float* op = acc_part + ((size_t)s * B_SZ + qb + l31) * D_SZ
                      + dbase + dt * 32 + 4 * half;
            #pragma unroll
            for (int rg = 0; rg < 4; rg++) {
                float4 v = make_float4(O[dt][4 * rg], O[dt][4 * rg + 1],
                                       O[dt][4 * rg + 2], O[dt][4 * rg + 3]);
                *(float4*)(op + 8 * rg) = v;
            }
        }
    }
}

// ---------------- COMBINE: merge splits + epilogue ----------------
__global__ __launch_bounds__(256) void combine_kernel(
    const float* __restrict__ x_t, const float* __restrict__ t,
    const float* __restrict__ m_part, const float* __restrict__ l_part,
    const float* __restrict__ acc_part, float* __restrict__ out, int nsplit)
{
    int q = blockIdx.x;
    int tid = threadIdx.x;
    float M = -1e30f;
    for (int s = 0; s < nsplit; s++) M = fmaxf(M, m_part[(size_t)s * B_SZ + q]);
    float L = 0.f;
    for (int s = 0; s < nsplit; s++)
        L += l_part[(size_t)s * B_SZ + q] * __expf(m_part[(size_t)s * B_SZ + q] - M);

    float tv = t[q];
    float bt = 1.0f - tv;
    float coeff = 1.0f + tv / bt;
    float invb = 1.0f / bt;
    float invL = 1.0f / L;

    int d = tid * 2;
    float2 w = make_float2(0.f, 0.f);
    for (int s = 0; s < nsplit; s++) {
        float sc = __expf(m_part[(size_t)s * B_SZ + q] - M);
        float2 av = *(const float2*)(acc_part + ((size_t)s * B_SZ + q) * D_SZ + d);
        w.x += sc * av.x; w.y += sc * av.y;
    }
    float2 xv = *(const float2*)(x_t + (size_t)q * D_SZ + d);
    float2 o;
    o.x = -invb * xv.x + coeff * w.x * invL;
    o.y = -invb * xv.y + coeff * w.y * invL;
    *(float2*)(out + (size_t)q * D_SZ + d) = o;
}

extern "C" void kernel_launch(void* const* d_in, const int* in_sizes, int n_in,
                              void* d_out, int out_size, void* d_ws, size_t ws_size,
                              hipStream_t stream) {
    const float* x_t = (const float*)d_in[0];
    const float* t   = (const float*)d_in[1];
    const float* ds  = (const float*)d_in[2];
    float* out = (float*)d_out;

    short* wsS = (short*)d_ws;
    short* Yh = wsS;                              // 51,200,000 shorts
    short* Yl = wsS + 51200000;
    short* Yt = wsS + 102400000;
    short* Xh = wsS + 153600000;                  // 524,288 shorts
    short* Xl = wsS + 154124288;
    float* fbase = (float*)((char*)d_ws + 309297152);   // 16B-aligned
    float* norms = fbase;                         // 100,000 f32
    int nsplit = 16;
    while (nsplit > 1 &&
           309697152ULL + (size_t)nsplit * 1024 * 4 * (2 + 512) > ws_size)
        nsplit >>= 1;
    float* m_part = fbase + 100000;
    float* l_part = m_part + (size_t)nsplit * B_SZ;
    float* acc    = l_part + (size_t)nsplit * B_SZ;
    int chunk = 32 * ((N_SZ + 32 * nsplit - 1) / (32 * nsplit));

    pre_kernel<<<dim3(NBLK + 32), dim3(256), 0, stream>>>(ds, x_t, Yh, Yl, Yt, Xh, Xl, norms);
    attn_kernel<<<dim3(B_SZ / 32, nsplit), dim3(512), 0, stream>>>(
        t, Xh, Xl, Yh, Yl, Yt, norms, m_part, l_part, acc, chunk);
    combine_kernel<<<dim3(B_SZ), dim3(256), 0, stream>>>(
        x_t, t, m_part, l_part, acc, out, nsplit);
}